// Round 1
// baseline (1735.943 us; speedup 1.0000x reference)
//
#include <hip/hip_runtime.h>
#include <math.h>

// Problem constants (match reference)
#define B_TOK 16384
#define H_DIM 2048
#define NE    8
#define TOPK  2
#define HFD   512

// Expert-kernel tiling
#define TM 32     // tokens per block tile
#define BH 64     // H-chunk staged in LDS

// Workspace layout (bytes)
//  [0, 32)              counts[NE]            int
//  [1024, 1024+8*B*4)   bucket[NE][B_TOK]     int   entry = token*2 + slot
//  [next, +B*2*4)       wslot[B_TOK*2]        float softmax weight per slot
static constexpr size_t OFF_COUNTS = 0;
static constexpr size_t OFF_BUCKET = 1024;
static constexpr size_t OFF_WSLOT  = OFF_BUCKET + (size_t)NE * B_TOK * 4;  // 525312
// total ws use: 525312 + 131072 = 656384 bytes

// ---------------------------------------------------------------------------
// Gate: logits = x @ Wg + bg ; top-2 softmax ; bucket tokens per expert.
// One wave (64 lanes) per token.
// ---------------------------------------------------------------------------
__global__ __launch_bounds__(256)
void gate_kernel(const float* __restrict__ x,
                 const float* __restrict__ Wg,
                 const float* __restrict__ bg,
                 float* __restrict__ out_logits,
                 int*   __restrict__ counts,
                 int*   __restrict__ bucket,
                 float* __restrict__ wslot)
{
    const int tok  = (blockIdx.x * blockDim.x + threadIdx.x) >> 6;
    const int lane = threadIdx.x & 63;
    if (tok >= B_TOK) return;

    const float* xrow = x + (size_t)tok * H_DIM;

    float acc[NE];
    #pragma unroll
    for (int e = 0; e < NE; ++e) acc[e] = 0.f;

    #pragma unroll 4
    for (int i = 0; i < H_DIM / 64; ++i) {
        const int h = i * 64 + lane;
        const float xv = xrow[h];
        const float4* wgp = reinterpret_cast<const float4*>(Wg + (size_t)h * NE);
        const float4 wa = wgp[0];
        const float4 wb = wgp[1];
        acc[0] += xv * wa.x;  acc[1] += xv * wa.y;
        acc[2] += xv * wa.z;  acc[3] += xv * wa.w;
        acc[4] += xv * wb.x;  acc[5] += xv * wb.y;
        acc[6] += xv * wb.z;  acc[7] += xv * wb.w;
    }

    // butterfly reduce each expert sum across the 64-lane wave
    #pragma unroll
    for (int e = 0; e < NE; ++e) {
        #pragma unroll
        for (int off = 32; off > 0; off >>= 1)
            acc[e] += __shfl_xor(acc[e], off, 64);
    }

    if (lane == 0) {
        #pragma unroll
        for (int e = 0; e < NE; ++e) acc[e] += bg[e];

        // write logits (contiguous 32B-aligned)
        float4* lo = reinterpret_cast<float4*>(out_logits + (size_t)tok * NE);
        lo[0] = make_float4(acc[0], acc[1], acc[2], acc[3]);
        lo[1] = make_float4(acc[4], acc[5], acc[6], acc[7]);

        // top-2 (strict > keeps lowest index on ties, matching lax.top_k)
        int i0 = 0; float v0 = acc[0];
        #pragma unroll
        for (int e = 1; e < NE; ++e)
            if (acc[e] > v0) { v0 = acc[e]; i0 = e; }
        int i1 = -1; float v1 = -3.4e38f;
        #pragma unroll
        for (int e = 0; e < NE; ++e)
            if (e != i0 && acc[e] > v1) { v1 = acc[e]; i1 = e; }

        const float w0 = 1.f / (1.f + expf(v1 - v0));   // softmax([v0,v1])[0]
        const float w1 = 1.f - w0;

        const int p0 = atomicAdd(&counts[i0], 1);
        bucket[i0 * B_TOK + p0] = tok * 2;
        wslot[tok * 2] = w0;
        const int p1 = atomicAdd(&counts[i1], 1);
        bucket[i1 * B_TOK + p1] = tok * 2 + 1;
        wslot[tok * 2 + 1] = w1;
    }
}

// ---------------------------------------------------------------------------
// Expert: for tokens routed to expert e, o = gelu(x@W1[e] + b1[e]) . W2[e];
// out[b] += w_slot * o   (exactly two commutative atomic adds per token).
// Block: 256 threads = 2 token-halves x 128 f-threads; each thread owns
// 16 tokens x 4 f columns of the h-accumulator.
// ---------------------------------------------------------------------------
__global__ __launch_bounds__(256)
void expert_kernel(const float* __restrict__ x,
                   const float* __restrict__ W1,
                   const float* __restrict__ b1,
                   const float* __restrict__ W2,
                   const int*   __restrict__ counts,
                   const int*   __restrict__ bucket,
                   const float* __restrict__ wslot,
                   float* __restrict__ out_scores)
{
    const int tilesPerE = B_TOK / TM;            // 512
    const int e = blockIdx.x / tilesPerE;
    const int t = blockIdx.x % tilesPerE;
    const int n = counts[e];
    const int start = t * TM;
    if (start >= n) return;
    const int nt = min(TM, n - start);

    __shared__ float x_lds[TM][68];              // stride 68 spreads staging banks
    __shared__ int   toks[TM];
    __shared__ float o_lds[TM];

    const int tid = threadIdx.x;
    if (tid < TM) {
        toks[tid]  = (tid < nt) ? bucket[e * B_TOK + start + tid] : -1;
        o_lds[tid] = 0.f;
    }
    __syncthreads();

    const int half   = tid >> 7;                 // 0 or 1
    const int fg     = (tid & 127) * 4;          // f base (0..508)
    const int tmbase = half * 16;

    float acc[16][4];
    #pragma unroll
    for (int tm = 0; tm < 16; ++tm)
        #pragma unroll
        for (int c = 0; c < 4; ++c) acc[tm][c] = 0.f;

    const float* W1e = W1 + (size_t)e * H_DIM * HFD;

    // staging role: thread -> (row tm = tid>>3, 64B slice j = tid&7)
    const int s_tm = tid >> 3;
    const int s_j  = tid & 7;
    const int myent = toks[s_tm];
    const float* xsrc = (myent >= 0)
        ? x + (size_t)(myent >> 1) * H_DIM + s_j * 8 : nullptr;

    for (int h0 = 0; h0 < H_DIM; h0 += BH) {
        float4 va = make_float4(0.f, 0.f, 0.f, 0.f);
        float4 vb = va;
        if (myent >= 0) {
            va = *reinterpret_cast<const float4*>(xsrc + h0);
            vb = *reinterpret_cast<const float4*>(xsrc + h0 + 4);
        }
        __syncthreads();   // previous chunk's compute done
        *reinterpret_cast<float4*>(&x_lds[s_tm][s_j * 8])     = va;
        *reinterpret_cast<float4*>(&x_lds[s_tm][s_j * 8 + 4]) = vb;
        __syncthreads();

        const float* wp = W1e + (size_t)h0 * HFD + fg;
        #pragma unroll 4
        for (int hh = 0; hh < BH; hh += 4) {
            const float4 w0 = *reinterpret_cast<const float4*>(wp);
            const float4 w1 = *reinterpret_cast<const float4*>(wp + HFD);
            const float4 w2 = *reinterpret_cast<const float4*>(wp + 2 * HFD);
            const float4 w3 = *reinterpret_cast<const float4*>(wp + 3 * HFD);
            wp += 4 * HFD;
            #pragma unroll
            for (int tm = 0; tm < 16; ++tm) {
                const float4 xv = *reinterpret_cast<const float4*>(&x_lds[tmbase + tm][hh]);
                acc[tm][0] += xv.x * w0.x; acc[tm][1] += xv.x * w0.y;
                acc[tm][2] += xv.x * w0.z; acc[tm][3] += xv.x * w0.w;
                acc[tm][0] += xv.y * w1.x; acc[tm][1] += xv.y * w1.y;
                acc[tm][2] += xv.y * w1.z; acc[tm][3] += xv.y * w1.w;
                acc[tm][0] += xv.z * w2.x; acc[tm][1] += xv.z * w2.y;
                acc[tm][2] += xv.z * w2.z; acc[tm][3] += xv.z * w2.w;
                acc[tm][0] += xv.w * w3.x; acc[tm][1] += xv.w * w3.y;
                acc[tm][2] += xv.w * w3.z; acc[tm][3] += xv.w * w3.w;
            }
        }
    }

    // epilogue: bias + exact GELU + dot W2 (this thread's 4 f columns)
    const float4 bb = *reinterpret_cast<const float4*>(b1 + (size_t)e * HFD + fg);
    const float4 ww = *reinterpret_cast<const float4*>(W2 + (size_t)e * HFD + fg);
    const float kInvSqrt2 = 0.70710678118654752f;

    float po[16];
    #pragma unroll
    for (int tm = 0; tm < 16; ++tm) {
        float h0v = acc[tm][0] + bb.x;
        float h1v = acc[tm][1] + bb.y;
        float h2v = acc[tm][2] + bb.z;
        float h3v = acc[tm][3] + bb.w;
        float s = 0.f;
        s += 0.5f * h0v * (1.f + erff(h0v * kInvSqrt2)) * ww.x;
        s += 0.5f * h1v * (1.f + erff(h1v * kInvSqrt2)) * ww.y;
        s += 0.5f * h2v * (1.f + erff(h2v * kInvSqrt2)) * ww.z;
        s += 0.5f * h3v * (1.f + erff(h3v * kInvSqrt2)) * ww.w;
        po[tm] = s;
    }

    // reduce over the 64 lanes of this wave (all lanes share the token group)
    #pragma unroll
    for (int tm = 0; tm < 16; ++tm) {
        float s = po[tm];
        #pragma unroll
        for (int off = 32; off > 0; off >>= 1)
            s += __shfl_xor(s, off, 64);
        po[tm] = s;
    }
    if ((tid & 63) == 0) {
        #pragma unroll
        for (int tm = 0; tm < 16; ++tm)
            atomicAdd(&o_lds[tmbase + tm], po[tm]);   // 2 waves per token group
    }
    __syncthreads();

    if (tid < nt) {
        const int entry = toks[tid];
        const float o   = o_lds[tid];
        const float w   = wslot[entry];
        atomicAdd(&out_scores[entry >> 1], w * o);    // exactly 2 adds per token
    }
}

// ---------------------------------------------------------------------------
extern "C" void kernel_launch(void* const* d_in, const int* in_sizes, int n_in,
                              void* d_out, int out_size, void* d_ws, size_t ws_size,
                              hipStream_t stream)
{
    const float* x  = (const float*)d_in[0];   // [B, H]
    const float* W1 = (const float*)d_in[1];   // [E, H, HF]
    const float* b1 = (const float*)d_in[2];   // [E, HF]
    const float* W2 = (const float*)d_in[3];   // [E, HF]
    const float* Wg = (const float*)d_in[4];   // [H, E]
    const float* bg = (const float*)d_in[5];   // [E]

    float* out        = (float*)d_out;
    float* out_scores = out;                   // [B, 1]
    float* out_logits = out + B_TOK;           // [B, E]

    char* ws = (char*)d_ws;
    int*   counts = (int*)  (ws + OFF_COUNTS);
    int*   bucket = (int*)  (ws + OFF_BUCKET);
    float* wslot  = (float*)(ws + OFF_WSLOT);

    hipMemsetAsync(counts, 0, NE * sizeof(int), stream);
    hipMemsetAsync(out_scores, 0, B_TOK * sizeof(float), stream);

    gate_kernel<<<B_TOK / 4, 256, 0, stream>>>(x, Wg, bg, out_logits,
                                               counts, bucket, wslot);

    expert_kernel<<<NE * (B_TOK / TM), 256, 0, stream>>>(x, W1, b1, W2,
                                                         counts, bucket, wslot,
                                                         out_scores);
}

// Round 2
// 701.487 us; speedup vs baseline: 2.4747x; 2.4747x over previous
//
#include <hip/hip_runtime.h>
#include <math.h>

// Problem constants (match reference)
#define B_TOK 16384
#define H_DIM 2048
#define NE    8
#define TOPK  2
#define HFD   512

// Expert-kernel tiling
#define TM 128    // tokens per block tile (N dim of MFMA GEMM)
#define BK 64     // K chunk staged in LDS

// Workspace layout (bytes)
//  [0, 32)               counts[NE]              int
//  [1024, 1024+8*B*4)    bucket[NE][B_TOK]       int   entry = token*2 + slot
//  [525312, +B*2*4)      wslot[B_TOK*2]          float softmax weight per slot
//  [1MB, 1MB+16MB)       W1t[E][HFD][H_DIM]      bf16  (transposed W1)
static constexpr size_t OFF_COUNTS = 0;
static constexpr size_t OFF_BUCKET = 1024;
static constexpr size_t OFF_WSLOT  = OFF_BUCKET + (size_t)NE * B_TOK * 4;  // 525312
static constexpr size_t OFF_W1T    = 1u << 20;                              // 1 MiB
// total ws use: 1 MiB + 16 MiB = ~17.8 MB

typedef short bfrag __attribute__((ext_vector_type(8)));   // 8 bf16 (4 VGPR)
typedef float facc  __attribute__((ext_vector_type(16)));  // 32x32 accum

// fp32 -> bf16 (round-to-nearest-even; inputs are normal floats)
__device__ inline unsigned short f2bf(float f) {
    union { float f; unsigned u; } v; v.f = f;
    unsigned r = v.u + 0x7FFFu + ((v.u >> 16) & 1u);
    return (unsigned short)(r >> 16);
}
__device__ inline unsigned pack2(float lo, float hi) {
    return (unsigned)f2bf(lo) | ((unsigned)f2bf(hi) << 16);
}

__device__ inline void gload_lds16(const void* g, void* l) {
    __builtin_amdgcn_global_load_lds(
        (const __attribute__((address_space(1))) unsigned int*)g,
        (__attribute__((address_space(3))) unsigned int*)l, 16, 0, 0);
}

// ---------------------------------------------------------------------------
// Gate: logits = x @ Wg + bg ; top-2 softmax ; bucket tokens per expert.
// One wave (64 lanes) per token.
// ---------------------------------------------------------------------------
__global__ __launch_bounds__(256)
void gate_kernel(const float* __restrict__ x,
                 const float* __restrict__ Wg,
                 const float* __restrict__ bg,
                 float* __restrict__ out_logits,
                 int*   __restrict__ counts,
                 int*   __restrict__ bucket,
                 float* __restrict__ wslot)
{
    const int tok  = (blockIdx.x * blockDim.x + threadIdx.x) >> 6;
    const int lane = threadIdx.x & 63;
    if (tok >= B_TOK) return;

    const float* xrow = x + (size_t)tok * H_DIM;

    float acc[NE];
    #pragma unroll
    for (int e = 0; e < NE; ++e) acc[e] = 0.f;

    #pragma unroll 4
    for (int i = 0; i < H_DIM / 64; ++i) {
        const int h = i * 64 + lane;
        const float xv = xrow[h];
        const float4* wgp = reinterpret_cast<const float4*>(Wg + (size_t)h * NE);
        const float4 wa = wgp[0];
        const float4 wb = wgp[1];
        acc[0] += xv * wa.x;  acc[1] += xv * wa.y;
        acc[2] += xv * wa.z;  acc[3] += xv * wa.w;
        acc[4] += xv * wb.x;  acc[5] += xv * wb.y;
        acc[6] += xv * wb.z;  acc[7] += xv * wb.w;
    }

    #pragma unroll
    for (int e = 0; e < NE; ++e) {
        #pragma unroll
        for (int off = 32; off > 0; off >>= 1)
            acc[e] += __shfl_xor(acc[e], off, 64);
    }

    if (lane == 0) {
        #pragma unroll
        for (int e = 0; e < NE; ++e) acc[e] += bg[e];

        float4* lo = reinterpret_cast<float4*>(out_logits + (size_t)tok * NE);
        lo[0] = make_float4(acc[0], acc[1], acc[2], acc[3]);
        lo[1] = make_float4(acc[4], acc[5], acc[6], acc[7]);

        int i0 = 0; float v0 = acc[0];
        #pragma unroll
        for (int e = 1; e < NE; ++e)
            if (acc[e] > v0) { v0 = acc[e]; i0 = e; }
        int i1 = -1; float v1 = -3.4e38f;
        #pragma unroll
        for (int e = 0; e < NE; ++e)
            if (e != i0 && acc[e] > v1) { v1 = acc[e]; i1 = e; }

        const float w0 = 1.f / (1.f + expf(v1 - v0));
        const float w1 = 1.f - w0;

        const int p0 = atomicAdd(&counts[i0], 1);
        bucket[i0 * B_TOK + p0] = tok * 2;
        wslot[tok * 2] = w0;
        const int p1 = atomicAdd(&counts[i1], 1);
        bucket[i1 * B_TOK + p1] = tok * 2 + 1;
        wslot[tok * 2 + 1] = w1;
    }
}

// ---------------------------------------------------------------------------
// Convert + transpose: W1 [E][H][HF] fp32 -> W1t [E][HF][H] bf16.
// Block handles a 64(k) x 64(f) tile through LDS.
// ---------------------------------------------------------------------------
__global__ __launch_bounds__(256)
void transpose_w1_kernel(const float* __restrict__ W1,
                         unsigned short* __restrict__ W1t)
{
    const int b  = blockIdx.x;          // e*256 + kb*8 + fb
    const int e  = b >> 8;
    const int rm = b & 255;
    const int k0 = (rm >> 3) * 64;
    const int f0 = (rm & 7) * 64;
    const int t  = threadIdx.x;

    __shared__ unsigned short T[64][72];   // [f][k], padded rows (144 B)

    #pragma unroll
    for (int r = 0; r < 4; ++r) {
        const int kk = r * 16 + (t >> 4);
        const int ff = (t & 15) * 4;
        const float4 v = *reinterpret_cast<const float4*>(
            W1 + ((size_t)(e * H_DIM + k0 + kk) * HFD) + f0 + ff);
        T[ff + 0][kk] = f2bf(v.x);
        T[ff + 1][kk] = f2bf(v.y);
        T[ff + 2][kk] = f2bf(v.z);
        T[ff + 3][kk] = f2bf(v.w);
    }
    __syncthreads();

    #pragma unroll
    for (int s = 0; s < 2; ++s) {
        const int idx  = s * 256 + t;
        const int f    = idx >> 3;
        const int slot = idx & 7;
        const uint4 val = *reinterpret_cast<const uint4*>(&T[f][slot * 8]);
        *reinterpret_cast<uint4*>(
            W1t + ((size_t)(e * HFD + f0 + f) * H_DIM) + k0 + slot * 8) = val;
    }
}

// ---------------------------------------------------------------------------
// Expert MFMA kernel. Per (expert, 128-token tile):
//   D[f][tok] = sum_k W1t[f][k] * x[tok][k]   (bf16 MFMA, fp32 accum)
// then per token: o = sum_f gelu(D + b1[f]) * W2[f]; out[tok] += wslot * o.
// 512 threads = 8 waves (4 f-groups x 2 token-groups), mfma_f32_32x32x16_bf16,
// 4(m) x 2(n) fragments per wave. LDS tiles XOR-swizzled (slot ^= row&7).
// ---------------------------------------------------------------------------
__global__ __launch_bounds__(512, 2)
void expert_mfma_kernel(const float* __restrict__ x,
                        const unsigned short* __restrict__ W1t,
                        const float* __restrict__ b1,
                        const float* __restrict__ W2,
                        const int*   __restrict__ counts,
                        const int*   __restrict__ bucket,
                        const float* __restrict__ wslot,
                        float* __restrict__ out_scores)
{
    const int tilesPerE = B_TOK / TM;     // 128
    const int e = blockIdx.x / tilesPerE;
    const int t = blockIdx.x % tilesPerE;
    const int n = counts[e];
    const int start = t * TM;
    if (start >= n) return;
    const int nt = min(TM, n - start);

    __shared__ unsigned short Alds[512 * 64];   // W1t tile (64 KB), swizzled
    __shared__ unsigned short Xlds[TM * 64];    // x tile  (16 KB), swizzled
    __shared__ int   toks[TM];
    __shared__ float o_part[4][TM];

    const int tid = threadIdx.x;
    if (tid < TM) toks[tid] = (tid < nt) ? bucket[e * B_TOK + start + tid] : -1;
    __syncthreads();

    const int w   = tid >> 6;    // wave 0..7
    const int l   = tid & 63;
    const int lo5 = l & 31;
    const int hi  = l >> 5;
    const int fr  = w & 3;       // f-group   (128 rows)
    const int tc  = w >> 2;      // tok-group (64 cols)

    const unsigned short* W1te = W1t + (size_t)e * HFD * H_DIM;

    // x staging role: thread -> (row xr = tid>>2, quarter xq = tid&3)
    const int xr = tid >> 2;
    const int xq = tid & 3;
    const int xent = toks[xr];
    const float* xsrc = (xent >= 0)
        ? x + (size_t)(xent >> 1) * H_DIM + xq * 16 : nullptr;

    facc acc[4][2];
    #pragma unroll
    for (int m = 0; m < 4; ++m)
        #pragma unroll
        for (int nb = 0; nb < 2; ++nb)
            #pragma unroll
            for (int r = 0; r < 16; ++r) acc[m][nb][r] = 0.f;

    for (int k0 = 0; k0 < H_DIM; k0 += BK) {
        // issue x global loads early (regs; no LDS conflict with prior compute)
        float4 v0 = make_float4(0.f,0.f,0.f,0.f), v1 = v0, v2 = v0, v3 = v0;
        if (xent >= 0) {
            v0 = *reinterpret_cast<const float4*>(xsrc + k0);
            v1 = *reinterpret_cast<const float4*>(xsrc + k0 + 4);
            v2 = *reinterpret_cast<const float4*>(xsrc + k0 + 8);
            v3 = *reinterpret_cast<const float4*>(xsrc + k0 + 12);
        }
        __syncthreads();   // previous chunk's frag reads done

        // A tile: 8 x global_load_lds (1 KB per wave-instr), pre-swizzled src
        #pragma unroll
        for (int it = 0; it < 8; ++it) {
            const int chunk = w * 8 + it;
            const int fA    = chunk * 8 + (l >> 3);
            const int slot  = l & 7;
            const int kk    = k0 + (((slot) ^ (fA & 7)) << 3);
            gload_lds16(W1te + (size_t)fA * H_DIM + kk,
                        Alds + chunk * 512 + l * 8);
        }

        // X tile: convert + swizzled ds_write_b128 (2 slices per thread)
        {
            uint4 p0, p1;
            p0.x = pack2(v0.x, v0.y); p0.y = pack2(v0.z, v0.w);
            p0.z = pack2(v1.x, v1.y); p0.w = pack2(v1.z, v1.w);
            p1.x = pack2(v2.x, v2.y); p1.y = pack2(v2.z, v2.w);
            p1.z = pack2(v3.x, v3.y); p1.w = pack2(v3.z, v3.w);
            const int s0 = (2 * xq)     ^ (xr & 7);
            const int s1 = (2 * xq + 1) ^ (xr & 7);
            *reinterpret_cast<uint4*>(&Xlds[xr * 64 + s0 * 8]) = p0;
            *reinterpret_cast<uint4*>(&Xlds[xr * 64 + s1 * 8]) = p1;
        }
        __syncthreads();   // stage complete (compiler drains vmcnt/lgkmcnt)

        #pragma unroll
        for (int ks = 0; ks < 4; ++ks) {
            bfrag a[4], bb[2];
            #pragma unroll
            for (int m = 0; m < 4; ++m) {
                const int frow  = fr * 128 + m * 32 + lo5;
                const int slice = (ks * 2 + hi) ^ (frow & 7);
                a[m] = *reinterpret_cast<const bfrag*>(&Alds[frow * 64 + slice * 8]);
            }
            #pragma unroll
            for (int nb = 0; nb < 2; ++nb) {
                const int trow  = tc * 64 + nb * 32 + lo5;
                const int slice = (ks * 2 + hi) ^ (trow & 7);
                bb[nb] = *reinterpret_cast<const bfrag*>(&Xlds[trow * 64 + slice * 8]);
            }
            #pragma unroll
            for (int m = 0; m < 4; ++m)
                #pragma unroll
                for (int nb = 0; nb < 2; ++nb)
                    acc[m][nb] = __builtin_amdgcn_mfma_f32_32x32x16_bf16(
                        a[m], bb[nb], acc[m][nb], 0, 0, 0);
        }
    }

    // Epilogue: bias + exact GELU + W2 dot, reduce over f.
    const float* b1e = b1 + e * HFD;
    const float* W2e = W2 + e * HFD;
    const float kInvSqrt2 = 0.70710678118654752f;

    float po0 = 0.f, po1 = 0.f;
    #pragma unroll
    for (int m = 0; m < 4; ++m) {
        const int base = fr * 128 + m * 32 + 4 * hi;
        #pragma unroll
        for (int r = 0; r < 16; ++r) {
            const int frow = base + (r & 3) + 8 * (r >> 2);
            const float bv = b1e[frow];
            const float wv = W2e[frow];
            const float h0 = acc[m][0][r] + bv;
            const float h1 = acc[m][1][r] + bv;
            po0 += 0.5f * h0 * (1.f + erff(h0 * kInvSqrt2)) * wv;
            po1 += 0.5f * h1 * (1.f + erff(h1 * kInvSqrt2)) * wv;
        }
    }
    po0 += __shfl_xor(po0, 32, 64);
    po1 += __shfl_xor(po1, 32, 64);

    const int col = tc * 64 + hi * 32 + lo5;
    o_part[fr][col] = hi ? po1 : po0;
    __syncthreads();

    if (tid < TM) {
        const int entry = toks[tid];
        if (entry >= 0) {
            const float o = o_part[0][tid] + o_part[1][tid]
                          + o_part[2][tid] + o_part[3][tid];
            atomicAdd(&out_scores[entry >> 1], wslot[entry] * o);
        }
    }
}

// ---------------------------------------------------------------------------
extern "C" void kernel_launch(void* const* d_in, const int* in_sizes, int n_in,
                              void* d_out, int out_size, void* d_ws, size_t ws_size,
                              hipStream_t stream)
{
    const float* x  = (const float*)d_in[0];   // [B, H]
    const float* W1 = (const float*)d_in[1];   // [E, H, HF]
    const float* b1 = (const float*)d_in[2];   // [E, HF]
    const float* W2 = (const float*)d_in[3];   // [E, HF]
    const float* Wg = (const float*)d_in[4];   // [H, E]
    const float* bg = (const float*)d_in[5];   // [E]

    float* out        = (float*)d_out;
    float* out_scores = out;                   // [B, 1]
    float* out_logits = out + B_TOK;           // [B, E]

    char* ws = (char*)d_ws;
    int*            counts = (int*)           (ws + OFF_COUNTS);
    int*            bucket = (int*)           (ws + OFF_BUCKET);
    float*          wslot  = (float*)         (ws + OFF_WSLOT);
    unsigned short* W1t    = (unsigned short*)(ws + OFF_W1T);

    hipMemsetAsync(counts, 0, NE * sizeof(int), stream);
    hipMemsetAsync(out_scores, 0, B_TOK * sizeof(float), stream);

    transpose_w1_kernel<<<NE * 256, 256, 0, stream>>>(W1, W1t);

    gate_kernel<<<B_TOK / 4, 256, 0, stream>>>(x, Wg, bg, out_logits,
                                               counts, bucket, wslot);

    expert_mfma_kernel<<<NE * (B_TOK / TM), 512, 0, stream>>>(
        x, W1t, b1, W2, counts, bucket, wslot, out_scores);
}

// Round 3
// 350.058 us; speedup vs baseline: 4.9590x; 2.0039x over previous
//
#include <hip/hip_runtime.h>
#include <math.h>

// Problem constants (match reference)
#define B_TOK 16384
#define H_DIM 2048
#define NE    8
#define TOPK  2
#define HFD   512

// Expert-kernel tiling
#define TM 128    // tokens per block tile (N dim of MFMA GEMM)
#define BK 64     // K chunk staged in LDS

// Workspace layout (bytes)
//  [0, 32)               counts[NE]              int
//  [1024, 1024+8*B*4)    bucket[NE][B_TOK]       int   entry = token*2 + slot
//  [525312, +B*2*4)      wslot[B_TOK*2]          float softmax weight per slot
//  [656384, +B*4)        route[B_TOK]            int   i0 | (i1<<8)
//  [720896, +64KB)       WgT[NE][H_DIM]          float (transposed gate W)
//  [1MB, 1MB+16MB)       W1t[E][HFD][H_DIM]      bf16  (transposed W1)
static constexpr size_t OFF_COUNTS = 0;
static constexpr size_t OFF_BUCKET = 1024;
static constexpr size_t OFF_WSLOT  = OFF_BUCKET + (size_t)NE * B_TOK * 4;  // 525312
static constexpr size_t OFF_ROUTE  = OFF_WSLOT + (size_t)B_TOK * 2 * 4;   // 656384
static constexpr size_t OFF_WGT    = 720896;
static constexpr size_t OFF_W1T    = 1u << 20;                              // 1 MiB
// total ws use: 1 MiB + 16 MiB = ~17.8 MB

typedef short bfrag __attribute__((ext_vector_type(8)));   // 8 bf16 (4 VGPR)
typedef float facc  __attribute__((ext_vector_type(16)));  // 32x32 accum

// fp32 -> bf16 (round-to-nearest-even; inputs are normal floats)
__device__ inline unsigned short f2bf(float f) {
    union { float f; unsigned u; } v; v.f = f;
    unsigned r = v.u + 0x7FFFu + ((v.u >> 16) & 1u);
    return (unsigned short)(r >> 16);
}
__device__ inline unsigned pack2(float lo, float hi) {
    return (unsigned)f2bf(lo) | ((unsigned)f2bf(hi) << 16);
}

__device__ inline void gload_lds16(const void* g, void* l) {
    __builtin_amdgcn_global_load_lds(
        (const __attribute__((address_space(1))) unsigned int*)g,
        (__attribute__((address_space(3))) unsigned int*)l, 16, 0, 0);
}

// ---------------------------------------------------------------------------
// Transpose gate weights: Wg [H][E] -> WgT [E][H].  One block, 256 threads.
// ---------------------------------------------------------------------------
__global__ __launch_bounds__(256)
void wg_transpose_kernel(const float* __restrict__ Wg,
                         float* __restrict__ WgT)
{
    const int t = threadIdx.x;
    #pragma unroll
    for (int rep = 0; rep < H_DIM / 256; ++rep) {
        const int h = rep * 256 + t;
        const float4 a = *reinterpret_cast<const float4*>(Wg + (size_t)h * NE);
        const float4 b = *reinterpret_cast<const float4*>(Wg + (size_t)h * NE + 4);
        WgT[0 * H_DIM + h] = a.x;  WgT[1 * H_DIM + h] = a.y;
        WgT[2 * H_DIM + h] = a.z;  WgT[3 * H_DIM + h] = a.w;
        WgT[4 * H_DIM + h] = b.x;  WgT[5 * H_DIM + h] = b.y;
        WgT[6 * H_DIM + h] = b.z;  WgT[7 * H_DIM + h] = b.w;
    }
}

// ---------------------------------------------------------------------------
// Gate logits (atomic-free): one wave per token, float4 x loads.
// Writes logits, per-token softmax weights, and packed top-2 route.
// ---------------------------------------------------------------------------
__global__ __launch_bounds__(256)
void gate_logits_kernel(const float* __restrict__ x,
                        const float* __restrict__ WgT,
                        const float* __restrict__ bg,
                        float* __restrict__ out_logits,
                        float* __restrict__ wslot,
                        int*   __restrict__ route)
{
    const int tok  = (blockIdx.x * blockDim.x + threadIdx.x) >> 6;
    const int lane = threadIdx.x & 63;
    if (tok >= B_TOK) return;

    const float* xrow = x + (size_t)tok * H_DIM;

    float acc[NE];
    #pragma unroll
    for (int e = 0; e < NE; ++e) acc[e] = 0.f;

    #pragma unroll 2
    for (int i = 0; i < H_DIM / 256; ++i) {
        const int h = i * 256 + 4 * lane;
        const float4 xv = *reinterpret_cast<const float4*>(xrow + h);
        #pragma unroll
        for (int e = 0; e < NE; ++e) {
            const float4 wv = *reinterpret_cast<const float4*>(WgT + (size_t)e * H_DIM + h);
            acc[e] += xv.x * wv.x + xv.y * wv.y + xv.z * wv.z + xv.w * wv.w;
        }
    }

    #pragma unroll
    for (int e = 0; e < NE; ++e) {
        #pragma unroll
        for (int off = 32; off > 0; off >>= 1)
            acc[e] += __shfl_xor(acc[e], off, 64);
    }

    if (lane == 0) {
        #pragma unroll
        for (int e = 0; e < NE; ++e) acc[e] += bg[e];

        float4* lo = reinterpret_cast<float4*>(out_logits + (size_t)tok * NE);
        lo[0] = make_float4(acc[0], acc[1], acc[2], acc[3]);
        lo[1] = make_float4(acc[4], acc[5], acc[6], acc[7]);

        int i0 = 0; float v0 = acc[0];
        #pragma unroll
        for (int e = 1; e < NE; ++e)
            if (acc[e] > v0) { v0 = acc[e]; i0 = e; }
        int i1 = -1; float v1 = -3.4e38f;
        #pragma unroll
        for (int e = 0; e < NE; ++e)
            if (e != i0 && acc[e] > v1) { v1 = acc[e]; i1 = e; }

        const float w0 = 1.f / (1.f + expf(v1 - v0));
        wslot[tok * 2]     = w0;
        wslot[tok * 2 + 1] = 1.f - w0;
        route[tok] = i0 | (i1 << 8);
    }
}

// ---------------------------------------------------------------------------
// Route/bucket: LDS-aggregated per-block histogram; 8 global atomics/block.
// 16 blocks x 1024 threads, thread-per-token.
// ---------------------------------------------------------------------------
__global__ __launch_bounds__(1024)
void route_kernel(const int* __restrict__ route,
                  int* __restrict__ counts,
                  int* __restrict__ bucket)
{
    __shared__ int lcnt[NE];
    __shared__ int lbase[NE];
    const int tid = threadIdx.x;
    const int tok = blockIdx.x * 1024 + tid;

    if (tid < NE) lcnt[tid] = 0;
    __syncthreads();

    const int rt = route[tok];
    const int i0 = rt & 255;
    const int i1 = rt >> 8;
    const int r0 = atomicAdd(&lcnt[i0], 1);
    const int r1 = atomicAdd(&lcnt[i1], 1);
    __syncthreads();

    if (tid < NE) lbase[tid] = atomicAdd(&counts[tid], lcnt[tid]);
    __syncthreads();

    bucket[i0 * B_TOK + lbase[i0] + r0] = tok * 2;
    bucket[i1 * B_TOK + lbase[i1] + r1] = tok * 2 + 1;
}

// ---------------------------------------------------------------------------
// Convert + transpose: W1 [E][H][HF] fp32 -> W1t [E][HF][H] bf16.
// ---------------------------------------------------------------------------
__global__ __launch_bounds__(256)
void transpose_w1_kernel(const float* __restrict__ W1,
                         unsigned short* __restrict__ W1t)
{
    const int b  = blockIdx.x;          // e*256 + kb*8 + fb
    const int e  = b >> 8;
    const int rm = b & 255;
    const int k0 = (rm >> 3) * 64;
    const int f0 = (rm & 7) * 64;
    const int t  = threadIdx.x;

    __shared__ unsigned short T[64][72];   // [f][k], padded rows

    #pragma unroll
    for (int r = 0; r < 4; ++r) {
        const int kk = r * 16 + (t >> 4);
        const int ff = (t & 15) * 4;
        const float4 v = *reinterpret_cast<const float4*>(
            W1 + ((size_t)(e * H_DIM + k0 + kk) * HFD) + f0 + ff);
        T[ff + 0][kk] = f2bf(v.x);
        T[ff + 1][kk] = f2bf(v.y);
        T[ff + 2][kk] = f2bf(v.z);
        T[ff + 3][kk] = f2bf(v.w);
    }
    __syncthreads();

    #pragma unroll
    for (int s = 0; s < 2; ++s) {
        const int idx  = s * 256 + t;
        const int f    = idx >> 3;
        const int slot = idx & 7;
        const uint4 val = *reinterpret_cast<const uint4*>(&T[f][slot * 8]);
        *reinterpret_cast<uint4*>(
            W1t + ((size_t)(e * HFD + f0 + f) * H_DIM) + k0 + slot * 8) = val;
    }
}

// ---------------------------------------------------------------------------
// Expert MFMA kernel (unchanged from round 2).
// ---------------------------------------------------------------------------
__global__ __launch_bounds__(512, 2)
void expert_mfma_kernel(const float* __restrict__ x,
                        const unsigned short* __restrict__ W1t,
                        const float* __restrict__ b1,
                        const float* __restrict__ W2,
                        const int*   __restrict__ counts,
                        const int*   __restrict__ bucket,
                        const float* __restrict__ wslot,
                        float* __restrict__ out_scores)
{
    const int tilesPerE = B_TOK / TM;     // 128
    const int e = blockIdx.x / tilesPerE;
    const int t = blockIdx.x % tilesPerE;
    const int n = counts[e];
    const int start = t * TM;
    if (start >= n) return;
    const int nt = min(TM, n - start);

    __shared__ unsigned short Alds[512 * 64];   // W1t tile (64 KB), swizzled
    __shared__ unsigned short Xlds[TM * 64];    // x tile  (16 KB), swizzled
    __shared__ int   toks[TM];
    __shared__ float o_part[4][TM];

    const int tid = threadIdx.x;
    if (tid < TM) toks[tid] = (tid < nt) ? bucket[e * B_TOK + start + tid] : -1;
    __syncthreads();

    const int w   = tid >> 6;    // wave 0..7
    const int l   = tid & 63;
    const int lo5 = l & 31;
    const int hi  = l >> 5;
    const int fr  = w & 3;       // f-group   (128 rows)
    const int tc  = w >> 2;      // tok-group (64 cols)

    const unsigned short* W1te = W1t + (size_t)e * HFD * H_DIM;

    const int xr = tid >> 2;
    const int xq = tid & 3;
    const int xent = toks[xr];
    const float* xsrc = (xent >= 0)
        ? x + (size_t)(xent >> 1) * H_DIM + xq * 16 : nullptr;

    facc acc[4][2];
    #pragma unroll
    for (int m = 0; m < 4; ++m)
        #pragma unroll
        for (int nb = 0; nb < 2; ++nb)
            #pragma unroll
            for (int r = 0; r < 16; ++r) acc[m][nb][r] = 0.f;

    for (int k0 = 0; k0 < H_DIM; k0 += BK) {
        float4 v0 = make_float4(0.f,0.f,0.f,0.f), v1 = v0, v2 = v0, v3 = v0;
        if (xent >= 0) {
            v0 = *reinterpret_cast<const float4*>(xsrc + k0);
            v1 = *reinterpret_cast<const float4*>(xsrc + k0 + 4);
            v2 = *reinterpret_cast<const float4*>(xsrc + k0 + 8);
            v3 = *reinterpret_cast<const float4*>(xsrc + k0 + 12);
        }
        __syncthreads();

        #pragma unroll
        for (int it = 0; it < 8; ++it) {
            const int chunk = w * 8 + it;
            const int fA    = chunk * 8 + (l >> 3);
            const int slot  = l & 7;
            const int kk    = k0 + (((slot) ^ (fA & 7)) << 3);
            gload_lds16(W1te + (size_t)fA * H_DIM + kk,
                        Alds + chunk * 512 + l * 8);
        }

        {
            uint4 p0, p1;
            p0.x = pack2(v0.x, v0.y); p0.y = pack2(v0.z, v0.w);
            p0.z = pack2(v1.x, v1.y); p0.w = pack2(v1.z, v1.w);
            p1.x = pack2(v2.x, v2.y); p1.y = pack2(v2.z, v2.w);
            p1.z = pack2(v3.x, v3.y); p1.w = pack2(v3.z, v3.w);
            const int s0 = (2 * xq)     ^ (xr & 7);
            const int s1 = (2 * xq + 1) ^ (xr & 7);
            *reinterpret_cast<uint4*>(&Xlds[xr * 64 + s0 * 8]) = p0;
            *reinterpret_cast<uint4*>(&Xlds[xr * 64 + s1 * 8]) = p1;
        }
        __syncthreads();

        #pragma unroll
        for (int ks = 0; ks < 4; ++ks) {
            bfrag a[4], bb[2];
            #pragma unroll
            for (int m = 0; m < 4; ++m) {
                const int frow  = fr * 128 + m * 32 + lo5;
                const int slice = (ks * 2 + hi) ^ (frow & 7);
                a[m] = *reinterpret_cast<const bfrag*>(&Alds[frow * 64 + slice * 8]);
            }
            #pragma unroll
            for (int nb = 0; nb < 2; ++nb) {
                const int trow  = tc * 64 + nb * 32 + lo5;
                const int slice = (ks * 2 + hi) ^ (trow & 7);
                bb[nb] = *reinterpret_cast<const bfrag*>(&Xlds[trow * 64 + slice * 8]);
            }
            #pragma unroll
            for (int m = 0; m < 4; ++m)
                #pragma unroll
                for (int nb = 0; nb < 2; ++nb)
                    acc[m][nb] = __builtin_amdgcn_mfma_f32_32x32x16_bf16(
                        a[m], bb[nb], acc[m][nb], 0, 0, 0);
        }
    }

    const float* b1e = b1 + e * HFD;
    const float* W2e = W2 + e * HFD;
    const float kInvSqrt2 = 0.70710678118654752f;

    float po0 = 0.f, po1 = 0.f;
    #pragma unroll
    for (int m = 0; m < 4; ++m) {
        const int base = fr * 128 + m * 32 + 4 * hi;
        #pragma unroll
        for (int r = 0; r < 16; ++r) {
            const int frow = base + (r & 3) + 8 * (r >> 2);
            const float bv = b1e[frow];
            const float wv = W2e[frow];
            const float h0 = acc[m][0][r] + bv;
            const float h1 = acc[m][1][r] + bv;
            po0 += 0.5f * h0 * (1.f + erff(h0 * kInvSqrt2)) * wv;
            po1 += 0.5f * h1 * (1.f + erff(h1 * kInvSqrt2)) * wv;
        }
    }
    po0 += __shfl_xor(po0, 32, 64);
    po1 += __shfl_xor(po1, 32, 64);

    const int col = tc * 64 + hi * 32 + lo5;
    o_part[fr][col] = hi ? po1 : po0;
    __syncthreads();

    if (tid < TM) {
        const int entry = toks[tid];
        if (entry >= 0) {
            const float o = o_part[0][tid] + o_part[1][tid]
                          + o_part[2][tid] + o_part[3][tid];
            atomicAdd(&out_scores[entry >> 1], wslot[entry] * o);
        }
    }
}

// ---------------------------------------------------------------------------
extern "C" void kernel_launch(void* const* d_in, const int* in_sizes, int n_in,
                              void* d_out, int out_size, void* d_ws, size_t ws_size,
                              hipStream_t stream)
{
    const float* x  = (const float*)d_in[0];   // [B, H]
    const float* W1 = (const float*)d_in[1];   // [E, H, HF]
    const float* b1 = (const float*)d_in[2];   // [E, HF]
    const float* W2 = (const float*)d_in[3];   // [E, HF]
    const float* Wg = (const float*)d_in[4];   // [H, E]
    const float* bg = (const float*)d_in[5];   // [E]

    float* out        = (float*)d_out;
    float* out_scores = out;                   // [B, 1]
    float* out_logits = out + B_TOK;           // [B, E]

    char* ws = (char*)d_ws;
    int*            counts = (int*)           (ws + OFF_COUNTS);
    int*            bucket = (int*)           (ws + OFF_BUCKET);
    float*          wslot  = (float*)         (ws + OFF_WSLOT);
    int*            route  = (int*)           (ws + OFF_ROUTE);
    float*          WgT    = (float*)         (ws + OFF_WGT);
    unsigned short* W1t    = (unsigned short*)(ws + OFF_W1T);

    hipMemsetAsync(counts, 0, NE * sizeof(int), stream);
    hipMemsetAsync(out_scores, 0, B_TOK * sizeof(float), stream);

    wg_transpose_kernel<<<1, 256, 0, stream>>>(Wg, WgT);

    transpose_w1_kernel<<<NE * 256, 256, 0, stream>>>(W1, W1t);

    gate_logits_kernel<<<B_TOK / 4, 256, 0, stream>>>(x, WgT, bg, out_logits,
                                                      wslot, route);

    route_kernel<<<B_TOK / 1024, 1024, 0, stream>>>(route, counts, bucket);

    expert_mfma_kernel<<<NE * (B_TOK / TM), 512, 0, stream>>>(
        x, W1t, b1, W2, counts, bucket, wslot, out_scores);
}

// Round 4
// 299.829 us; speedup vs baseline: 5.7898x; 1.1675x over previous
//
#include <hip/hip_runtime.h>
#include <math.h>

// Problem constants (match reference)
#define B_TOK 16384
#define H_DIM 2048
#define NE    8
#define TOPK  2
#define HFD   512

// Expert-kernel tiling
#define TM 64     // tokens per block tile
#define BK 32     // K chunk per pipeline stage
#define NKSTEP (H_DIM / BK)   // 64

// Workspace layout (bytes)
static constexpr size_t OFF_COUNTS = 0;                                     // 32 B
static constexpr size_t OFF_BUCKET = 1024;                                  // 512 KB
static constexpr size_t OFF_WSLOT  = OFF_BUCKET + (size_t)NE * B_TOK * 4;   // 525312
static constexpr size_t OFF_ROUTE  = OFF_WSLOT + (size_t)B_TOK * 2 * 4;     // 656384
static constexpr size_t OFF_WGT    = 720896;                                // 64 KB
static constexpr size_t OFF_W1TS   = 1u << 20;                              // 16 MB
static constexpr size_t OFF_XB     = OFF_W1TS + (size_t)NE * HFD * H_DIM * 2; // 17 MB
// xb = 64 MB -> total ws use ~81 MB

typedef short bfrag __attribute__((ext_vector_type(8)));   // 8 bf16 (4 VGPR)
typedef float facc  __attribute__((ext_vector_type(16)));  // 32x32 accum

// fp32 -> bf16 (round-to-nearest-even)
__device__ inline unsigned short f2bf(float f) {
    union { float f; unsigned u; } v; v.f = f;
    unsigned r = v.u + 0x7FFFu + ((v.u >> 16) & 1u);
    return (unsigned short)(r >> 16);
}
__device__ inline unsigned pack2(float lo, float hi) {
    return (unsigned)f2bf(lo) | ((unsigned)f2bf(hi) << 16);
}

__device__ __forceinline__ void gload_lds16(const void* g, void* l) {
    __builtin_amdgcn_global_load_lds(
        (const __attribute__((address_space(1))) unsigned int*)g,
        (__attribute__((address_space(3))) unsigned int*)l, 16, 0, 0);
}

// ---------------------------------------------------------------------------
// Transpose gate weights: Wg [H][E] -> WgT [E][H].
// ---------------------------------------------------------------------------
__global__ __launch_bounds__(256)
void wg_transpose_kernel(const float* __restrict__ Wg,
                         float* __restrict__ WgT)
{
    const int t = threadIdx.x;
    #pragma unroll
    for (int rep = 0; rep < H_DIM / 256; ++rep) {
        const int h = rep * 256 + t;
        const float4 a = *reinterpret_cast<const float4*>(Wg + (size_t)h * NE);
        const float4 b = *reinterpret_cast<const float4*>(Wg + (size_t)h * NE + 4);
        WgT[0 * H_DIM + h] = a.x;  WgT[1 * H_DIM + h] = a.y;
        WgT[2 * H_DIM + h] = a.z;  WgT[3 * H_DIM + h] = a.w;
        WgT[4 * H_DIM + h] = b.x;  WgT[5 * H_DIM + h] = b.y;
        WgT[6 * H_DIM + h] = b.z;  WgT[7 * H_DIM + h] = b.w;
    }
}

// ---------------------------------------------------------------------------
// Prep W1: [E][H][HF] fp32 -> k-slot-major bf16 image:
//   W1ts[e][kstep][slot(0..3)][f(0..511)][j(0..7)]  (element k = kstep*32+slot*8+j)
// Each (e,kstep) block of 16384 elems (32 KB) is exactly one LDS A-stage image.
// ---------------------------------------------------------------------------
__global__ __launch_bounds__(256)
void prep_w1_kernel(const float* __restrict__ W1,
                    unsigned short* __restrict__ W1ts)
{
    const int blk   = blockIdx.x;       // e*64 + kstep
    const int e     = blk >> 6;
    const int kstep = blk & 63;
    const int tid   = threadIdx.x;

    const float* src = W1 + ((size_t)e * H_DIM + kstep * BK) * HFD;
    unsigned short* dst = W1ts + (size_t)e * (HFD * H_DIM) + (size_t)kstep * (BK * HFD);

    #pragma unroll
    for (int s = 0; s < 4; ++s) {
        #pragma unroll
        for (int fh = 0; fh < 2; ++fh) {
            const int f = fh * 256 + tid;
            float v[8];
            #pragma unroll
            for (int j = 0; j < 8; ++j)
                v[j] = src[(size_t)(s * 8 + j) * HFD + f];   // coalesced across lanes
            uint4 p;
            p.x = pack2(v[0], v[1]); p.y = pack2(v[2], v[3]);
            p.z = pack2(v[4], v[5]); p.w = pack2(v[6], v[7]);
            *reinterpret_cast<uint4*>(dst + s * 4096 + f * 8) = p;
        }
    }
}

// ---------------------------------------------------------------------------
// Gate logits + x->bf16 conversion (atomic-free). One wave per token.
// ---------------------------------------------------------------------------
__global__ __launch_bounds__(256)
void gate_logits_kernel(const float* __restrict__ x,
                        const float* __restrict__ WgT,
                        const float* __restrict__ bg,
                        float* __restrict__ out_logits,
                        float* __restrict__ wslot,
                        int*   __restrict__ route,
                        unsigned short* __restrict__ xb)
{
    const int tok  = (blockIdx.x * blockDim.x + threadIdx.x) >> 6;
    const int lane = threadIdx.x & 63;
    if (tok >= B_TOK) return;

    const float* xrow = x + (size_t)tok * H_DIM;
    unsigned short* xbrow = xb + (size_t)tok * H_DIM;

    float acc[NE];
    #pragma unroll
    for (int e = 0; e < NE; ++e) acc[e] = 0.f;

    #pragma unroll 2
    for (int i = 0; i < H_DIM / 256; ++i) {
        const int h = i * 256 + 4 * lane;
        const float4 xv = *reinterpret_cast<const float4*>(xrow + h);
        uint2 p;
        p.x = pack2(xv.x, xv.y);
        p.y = pack2(xv.z, xv.w);
        *reinterpret_cast<uint2*>(xbrow + h) = p;
        #pragma unroll
        for (int e = 0; e < NE; ++e) {
            const float4 wv = *reinterpret_cast<const float4*>(WgT + (size_t)e * H_DIM + h);
            acc[e] += xv.x * wv.x + xv.y * wv.y + xv.z * wv.z + xv.w * wv.w;
        }
    }

    #pragma unroll
    for (int e = 0; e < NE; ++e) {
        #pragma unroll
        for (int off = 32; off > 0; off >>= 1)
            acc[e] += __shfl_xor(acc[e], off, 64);
    }

    if (lane == 0) {
        #pragma unroll
        for (int e = 0; e < NE; ++e) acc[e] += bg[e];

        float4* lo = reinterpret_cast<float4*>(out_logits + (size_t)tok * NE);
        lo[0] = make_float4(acc[0], acc[1], acc[2], acc[3]);
        lo[1] = make_float4(acc[4], acc[5], acc[6], acc[7]);

        int i0 = 0; float v0 = acc[0];
        #pragma unroll
        for (int e = 1; e < NE; ++e)
            if (acc[e] > v0) { v0 = acc[e]; i0 = e; }
        int i1 = -1; float v1 = -3.4e38f;
        #pragma unroll
        for (int e = 0; e < NE; ++e)
            if (e != i0 && acc[e] > v1) { v1 = acc[e]; i1 = e; }

        const float w0 = 1.f / (1.f + expf(v1 - v0));
        wslot[tok * 2]     = w0;
        wslot[tok * 2 + 1] = 1.f - w0;
        route[tok] = i0 | (i1 << 8);
    }
}

// ---------------------------------------------------------------------------
// Route/bucket: LDS-aggregated histogram; 8 global atomics per block.
// ---------------------------------------------------------------------------
__global__ __launch_bounds__(1024)
void route_kernel(const int* __restrict__ route,
                  int* __restrict__ counts,
                  int* __restrict__ bucket)
{
    __shared__ int lcnt[NE];
    __shared__ int lbase[NE];
    const int tid = threadIdx.x;
    const int tok = blockIdx.x * 1024 + tid;

    if (tid < NE) lcnt[tid] = 0;
    __syncthreads();

    const int rt = route[tok];
    const int i0 = rt & 255;
    const int i1 = rt >> 8;
    const int r0 = atomicAdd(&lcnt[i0], 1);
    const int r1 = atomicAdd(&lcnt[i1], 1);
    __syncthreads();

    if (tid < NE) lbase[tid] = atomicAdd(&counts[tid], lcnt[tid]);
    __syncthreads();

    bucket[i0 * B_TOK + lbase[i0] + r0] = tok * 2;
    bucket[i1 * B_TOK + lbase[i1] + r1] = tok * 2 + 1;
}

// ---------------------------------------------------------------------------
// Expert MFMA kernel: 512 thr / 8 waves; wave w owns f rows [w*64, w*64+64);
// 64 tokens per block; BK=32 double-buffered via global_load_lds + counted
// vmcnt + raw barriers. k-slot-major LDS: conflict-free ds_read_b128.
// Expert pinned to XCD via e = blockIdx & 7 (W1ts[e] = 2 MB L2-resident).
// ---------------------------------------------------------------------------
__global__ __launch_bounds__(512, 4)
void expert_mfma_kernel(const unsigned short* __restrict__ xb,
                        const unsigned short* __restrict__ W1ts,
                        const float* __restrict__ b1,
                        const float* __restrict__ W2,
                        const int*   __restrict__ counts,
                        const int*   __restrict__ bucket,
                        const float* __restrict__ wslot,
                        float* __restrict__ out_scores)
{
    const int e = blockIdx.x & 7;
    const int t = blockIdx.x >> 3;
    const int n = counts[e];
    const int start = t * TM;
    if (start >= n) return;
    const int nt = min(TM, n - start);

    __shared__ unsigned short Abuf[2][4 * 4096];   // [slot][f][j]  32 KB each
    __shared__ unsigned short Xbuf[2][4 * 512];    // [slot][tok][j] 4 KB each
    __shared__ float o_part[8][TM];

    const int tid = threadIdx.x;
    const int w   = tid >> 6;
    const int l   = tid & 63;
    const int lo5 = l & 31;
    const int hi  = l >> 5;

    const unsigned short* W1e = W1ts + (size_t)e * (HFD * H_DIM);

    // X staging source: waves 0..3 load slot w for all 64 tokens (lane = token)
    const unsigned short* xsrc = nullptr;
    if (w < 4) {
        const int ent = bucket[e * B_TOK + start + min(l, nt - 1)];
        xsrc = xb + (size_t)(ent >> 1) * H_DIM + w * 8;
    }

    facc acc[2][2];
    #pragma unroll
    for (int m = 0; m < 2; ++m)
        #pragma unroll
        for (int nb = 0; nb < 2; ++nb)
            #pragma unroll
            for (int r = 0; r < 16; ++r) acc[m][nb][r] = 0.f;

    // ---- stage helper (4 A-chunks per wave + 1 X-chunk for waves 0..3) ----
    #define STAGE(KK, BUF) do {                                               \
        const unsigned short* asrc_ = W1e + (size_t)(KK) * (BK * HFD);        \
        const int c0_ = w * 4;                                                \
        gload_lds16(asrc_ + (c0_ + 0) * 512 + l * 8, &Abuf[BUF][(c0_ + 0) * 512 + l * 8]); \
        gload_lds16(asrc_ + (c0_ + 1) * 512 + l * 8, &Abuf[BUF][(c0_ + 1) * 512 + l * 8]); \
        gload_lds16(asrc_ + (c0_ + 2) * 512 + l * 8, &Abuf[BUF][(c0_ + 2) * 512 + l * 8]); \
        gload_lds16(asrc_ + (c0_ + 3) * 512 + l * 8, &Abuf[BUF][(c0_ + 3) * 512 + l * 8]); \
        if (w < 4) gload_lds16(xsrc + (size_t)(KK) * BK, &Xbuf[BUF][w * 512 + l * 8]);     \
    } while (0)

    STAGE(0, 0);

    for (int kk = 0; kk < NKSTEP; ++kk) {
        const int cur = kk & 1;
        if (kk < NKSTEP - 1) {
            STAGE(kk + 1, cur ^ 1);
            if (w < 4) asm volatile("s_waitcnt vmcnt(5)" ::: "memory");
            else       asm volatile("s_waitcnt vmcnt(4)" ::: "memory");
        } else {
            asm volatile("s_waitcnt vmcnt(0)" ::: "memory");
        }
        __builtin_amdgcn_s_barrier();   // current buffer visible to all waves

        #pragma unroll
        for (int ks = 0; ks < 2; ++ks) {
            const int slot = ks * 2 + hi;
            const bfrag a0 = *reinterpret_cast<const bfrag*>(
                &Abuf[cur][slot * 4096 + (w * 64 + lo5) * 8]);
            const bfrag a1 = *reinterpret_cast<const bfrag*>(
                &Abuf[cur][slot * 4096 + (w * 64 + 32 + lo5) * 8]);
            const bfrag b0 = *reinterpret_cast<const bfrag*>(
                &Xbuf[cur][slot * 512 + lo5 * 8]);
            const bfrag b1f = *reinterpret_cast<const bfrag*>(
                &Xbuf[cur][slot * 512 + (32 + lo5) * 8]);
            acc[0][0] = __builtin_amdgcn_mfma_f32_32x32x16_bf16(a0, b0,  acc[0][0], 0, 0, 0);
            acc[0][1] = __builtin_amdgcn_mfma_f32_32x32x16_bf16(a0, b1f, acc[0][1], 0, 0, 0);
            acc[1][0] = __builtin_amdgcn_mfma_f32_32x32x16_bf16(a1, b0,  acc[1][0], 0, 0, 0);
            acc[1][1] = __builtin_amdgcn_mfma_f32_32x32x16_bf16(a1, b1f, acc[1][1], 0, 0, 0);
        }
        __builtin_amdgcn_s_barrier();   // reads done before next overwrite
    }
    #undef STAGE

    // Epilogue: bias + exact GELU + W2 dot; reduce over f (rows).
    const float* b1e = b1 + e * HFD;
    const float* W2e = W2 + e * HFD;
    const float kInvSqrt2 = 0.70710678118654752f;

    float po0 = 0.f, po1 = 0.f;
    #pragma unroll
    for (int m = 0; m < 2; ++m) {
        const int base = w * 64 + m * 32 + 4 * hi;
        #pragma unroll
        for (int r = 0; r < 16; ++r) {
            const int frow = base + (r & 3) + 8 * (r >> 2);
            const float bv = b1e[frow];
            const float wv = W2e[frow];
            const float h0 = acc[m][0][r] + bv;
            const float h1 = acc[m][1][r] + bv;
            po0 += 0.5f * h0 * (1.f + erff(h0 * kInvSqrt2)) * wv;
            po1 += 0.5f * h1 * (1.f + erff(h1 * kInvSqrt2)) * wv;
        }
    }
    po0 += __shfl_xor(po0, 32, 64);
    po1 += __shfl_xor(po1, 32, 64);

    if (hi == 0) {
        o_part[w][lo5]      = po0;
        o_part[w][32 + lo5] = po1;
    }
    __syncthreads();

    if (tid < nt) {
        const int entry = bucket[e * B_TOK + start + tid];
        float o = 0.f;
        #pragma unroll
        for (int w8 = 0; w8 < 8; ++w8) o += o_part[w8][tid];
        atomicAdd(&out_scores[entry >> 1], wslot[entry] * o);
    }
}

// ---------------------------------------------------------------------------
extern "C" void kernel_launch(void* const* d_in, const int* in_sizes, int n_in,
                              void* d_out, int out_size, void* d_ws, size_t ws_size,
                              hipStream_t stream)
{
    const float* x  = (const float*)d_in[0];   // [B, H]
    const float* W1 = (const float*)d_in[1];   // [E, H, HF]
    const float* b1 = (const float*)d_in[2];   // [E, HF]
    const float* W2 = (const float*)d_in[3];   // [E, HF]
    const float* Wg = (const float*)d_in[4];   // [H, E]
    const float* bg = (const float*)d_in[5];   // [E]

    float* out        = (float*)d_out;
    float* out_scores = out;                   // [B, 1]
    float* out_logits = out + B_TOK;           // [B, E]

    char* ws = (char*)d_ws;
    int*            counts = (int*)           (ws + OFF_COUNTS);
    int*            bucket = (int*)           (ws + OFF_BUCKET);
    float*          wslot  = (float*)         (ws + OFF_WSLOT);
    int*            route  = (int*)           (ws + OFF_ROUTE);
    float*          WgT    = (float*)         (ws + OFF_WGT);
    unsigned short* W1ts   = (unsigned short*)(ws + OFF_W1TS);
    unsigned short* xb     = (unsigned short*)(ws + OFF_XB);

    hipMemsetAsync(counts, 0, NE * sizeof(int), stream);
    hipMemsetAsync(out_scores, 0, B_TOK * sizeof(float), stream);

    wg_transpose_kernel<<<1, 256, 0, stream>>>(Wg, WgT);

    prep_w1_kernel<<<NE * NKSTEP, 256, 0, stream>>>(W1, W1ts);

    gate_logits_kernel<<<B_TOK / 4, 256, 0, stream>>>(x, WgT, bg, out_logits,
                                                      wslot, route, xb);

    route_kernel<<<B_TOK / 1024, 1024, 0, stream>>>(route, counts, bucket);

    expert_mfma_kernel<<<NE * (B_TOK / TM), 512, 0, stream>>>(
        xb, W1ts, b1, W2, counts, bucket, wslot, out_scores);
}